// Round 6
// baseline (178.686 us; speedup 1.0000x reference)
//
#include <hip/hip_runtime.h>
#include <cstdint>
#include <cstddef>

#define B_ 8
#define N_ 2048
#define D_ 2048
#define E_ 64
#define CAP_ 64
#define NTOK (B_*N_)                  // 16384 tokens
#define GEMM_BLOCKS 256               // 64 tokens/block, 4 waves
#define FILLV_BLOCKS 2048
#define DC 64                         // d-tile
#define NTILE (D_/DC)                 // 32
#define MASK_ELEMS ((size_t)NTOK*(size_t)E_*(size_t)CAP_)   // 67108864 per output

typedef float f32x4 __attribute__((ext_vector_type(4)));
typedef short bf16x8 __attribute__((ext_vector_type(8)));
typedef unsigned int u32;
typedef u32 u32x2 __attribute__((ext_vector_type(2)));

__device__ __forceinline__ u32 f2bf(float f) {          // RNE f32 -> bf16 bits
  u32 u = __float_as_uint(f);
  return (u + 0x7fffu + ((u >> 16) & 1u)) >> 16;
}
__device__ __forceinline__ float bf2f(u32 b) { return __uint_as_float(b << 16); }

// K0: W[2048][64] f32 -> WhiT/WloT bf16, transposed to [e][d] and tile-swizzled:
// 16B-granule index = (t*64 + e)*8 + (g ^ (e&7)), holding d = t*64+g*8..+7 of expert e.
__global__ __launch_bounds__(256)
void k_wconv(const float* __restrict__ W, u32* __restrict__ whi, u32* __restrict__ wlo) {
  const int i = blockIdx.x * 256 + threadIdx.x;   // 16384 = (t,e,g)
  const int g = i & 7, e = (i >> 3) & 63, t = i >> 9;
  const int d0 = t * DC + g * 8;
  const int dst = ((t * 64 + e) * 8 + (g ^ (e & 7))) * 4;  // in u32 (8 bf16 = 4 u32)
  #pragma unroll
  for (int jj = 0; jj < 4; ++jj) {
    const float x0 = W[(size_t)(d0 + 2*jj    ) * E_ + e];
    const float x1 = W[(size_t)(d0 + 2*jj + 1) * E_ + e];
    const u32 h0 = f2bf(x0), h1 = f2bf(x1);
    const u32 l0 = f2bf(x0 - bf2f(h0)), l1 = f2bf(x1 - bf2f(h1));
    whi[dst + jj] = h0 | (h1 << 16);
    wlo[dst + jj] = l0 | (l1 << 16);
  }
}

// K1: split-bf16 MFMA logits GEMM + per-token softmax stats (no fill here).
__global__ __launch_bounds__(256)
void k_gemm(const float* __restrict__ X, const u32* __restrict__ whi,
            const u32* __restrict__ wlo, float* __restrict__ gate_ws,
            int* __restrict__ idx_ws, float* __restrict__ z_ws) {
  const int bid = blockIdx.x;

  // buf layout per 32KB half: XH 0 | XL 8192 | WH 16384 | WL 24576
  __shared__ __align__(16) char lds[2][32768];
  const int tid  = threadIdx.x;
  const int lane = tid & 63;
  const int wid  = __builtin_amdgcn_readfirstlane(tid >> 6);
  const int tokbase = bid * 64;
  const int woff = wid * 16;            // wave's 16-token panel
  const int rA = lane & 15, kg = lane >> 4;

  // X staging map: p in 0..3 -> chunk c = p*256+tid ; row r=c>>4, f32x4-col q=c&15
  int xr_r[4], xr_q[4], xw_off[4];
  #pragma unroll
  for (int p = 0; p < 4; ++p) {
    const int c = p*256 + tid;
    const int r = c >> 4, q = c & 15;
    xr_r[p] = r; xr_q[p] = q;
    xw_off[p] = r*128 + (((q >> 1) ^ (r & 7)) << 4) + ((q & 1) << 3);
  }
  const f32x4* xg   = (const f32x4*)X;
  const f32x4* whi4 = (const f32x4*)whi;
  const f32x4* wlo4 = (const f32x4*)wlo;

  f32x4 xr[4], wr[4];

#define XW_LOAD(t)                                                            \
  { _Pragma("unroll")                                                         \
    for (int p = 0; p < 4; ++p)                                               \
      xr[p] = xg[(size_t)(tokbase + xr_r[p])*512 + (size_t)(t)*16 + xr_q[p]]; \
    wr[0] = whi4[(size_t)(t)*512 + tid];                                      \
    wr[1] = whi4[(size_t)(t)*512 + 256 + tid];                                \
    wr[2] = wlo4[(size_t)(t)*512 + tid];                                      \
    wr[3] = wlo4[(size_t)(t)*512 + 256 + tid]; }

#define XW_STORE(buf)                                                         \
  { char* bq = lds[buf];                                                      \
    _Pragma("unroll")                                                         \
    for (int p = 0; p < 4; ++p) {                                             \
      const u32 h0 = f2bf(xr[p][0]), h1 = f2bf(xr[p][1]);                     \
      const u32 h2 = f2bf(xr[p][2]), h3 = f2bf(xr[p][3]);                     \
      const u32 l0 = f2bf(xr[p][0] - bf2f(h0)), l1 = f2bf(xr[p][1] - bf2f(h1)); \
      const u32 l2 = f2bf(xr[p][2] - bf2f(h2)), l3 = f2bf(xr[p][3] - bf2f(h3)); \
      u32x2 hp; hp[0] = h0 | (h1 << 16); hp[1] = h2 | (h3 << 16);             \
      u32x2 lp; lp[0] = l0 | (l1 << 16); lp[1] = l2 | (l3 << 16);             \
      *(u32x2*)(bq + xw_off[p])        = hp;                                  \
      *(u32x2*)(bq + 8192 + xw_off[p]) = lp;                                  \
    }                                                                         \
    *(f32x4*)(bq + 16384 +        tid*16) = wr[0];                            \
    *(f32x4*)(bq + 16384 + 4096 + tid*16) = wr[1];                            \
    *(f32x4*)(bq + 24576 +        tid*16) = wr[2];                            \
    *(f32x4*)(bq + 24576 + 4096 + tid*16) = wr[3]; }

  XW_LOAD(0);
  XW_STORE(0);
  __syncthreads();

  f32x4 acc[4];
  #pragma unroll
  for (int eb = 0; eb < 4; ++eb) { acc[eb][0]=0.f; acc[eb][1]=0.f; acc[eb][2]=0.f; acc[eb][3]=0.f; }

  const int tokrow = woff + rA;
  for (int t = 0; t < NTILE; ++t) {
    if (t + 1 < NTILE) XW_LOAD(t + 1);

    const char* bp = lds[t & 1];
    #pragma unroll
    for (int kk = 0; kk < 2; ++kk) {
      const int gA = ((kk*4 + kg) ^ (rA & 7)) << 4;       // tokrow&7 == rA&7
      const bf16x8 Ah = *(const bf16x8*)(bp +        tokrow*128 + gA);
      const bf16x8 Al = *(const bf16x8*)(bp + 8192 + tokrow*128 + gA);
      #pragma unroll
      for (int eb = 0; eb < 4; ++eb) {
        const int e  = eb*16 + rA;
        const int gB = ((kk*4 + kg) ^ (e & 7)) << 4;
        const bf16x8 Bh = *(const bf16x8*)(bp + 16384 + e*128 + gB);
        const bf16x8 Bl = *(const bf16x8*)(bp + 24576 + e*128 + gB);
        acc[eb] = __builtin_amdgcn_mfma_f32_16x16x32_bf16(Ah, Bh, acc[eb], 0, 0, 0);
        acc[eb] = __builtin_amdgcn_mfma_f32_16x16x32_bf16(Ah, Bl, acc[eb], 0, 0, 0);
        acc[eb] = __builtin_amdgcn_mfma_f32_16x16x32_bf16(Al, Bh, acc[eb], 0, 0, 0);
        acc[eb] = __builtin_amdgcn_mfma_f32_16x16x32_bf16(Al, Bl, acc[eb], 0, 0, 0);
      }
    }

    if (t + 1 < NTILE) XW_STORE((t + 1) & 1);
    __syncthreads();
  }

  // ---- epilogue: logits -> LDS [64 tok][65], per-wave butterfly softmax ----
  float* Lg = (float*)&lds[0][0];
  // C/D layout: col = lane&15 (expert within block), row = (lane>>4)*4 + reg
  #pragma unroll
  for (int eb = 0; eb < 4; ++eb)
    #pragma unroll
    for (int r = 0; r < 4; ++r)
      Lg[(woff + kg*4 + r)*65 + eb*16 + rA] = acc[eb][r];
  __syncthreads();

  #pragma unroll 1
  for (int i = 0; i < 16; ++i) {
    const int tkn = woff + i;
    const float v = Lg[tkn*65 + lane];       // lane = expert
    float vmax = v; int vidx = lane;
    #pragma unroll
    for (int m = 1; m < 64; m <<= 1) {
      const float om = __shfl_xor(vmax, m);
      const int   oi = __shfl_xor(vidx, m);
      if (om > vmax || (om == vmax && oi < vidx)) { vmax = om; vidx = oi; }
    }
    float se = expf(v - vmax);
    #pragma unroll
    for (int m = 1; m < 64; m <<= 1) se += __shfl_xor(se, m);
    if (lane == 0) {
      const int row = tokbase + tkn;
      gate_ws[row] = 1.0f / se;              // max softmax prob
      idx_ws[row]  = vidx;                   // argmax, first occurrence
      z_ws[row]    = vmax + logf(se);        // logsumexp
    }
  }
#undef XW_LOAD
#undef XW_STORE
}

// K2: routing. 1 block, 8 waves = 8 batches. Ballot-cumsum position-in-expert,
// packs code[t] = idx | pos<<8 (pos=255 if dropped), reduces z-loss to zacc.
__global__ __launch_bounds__(512)
void k_route(const float* __restrict__ gate_ws, const int* __restrict__ idx_ws,
             const float* __restrict__ z_ws, u32* __restrict__ code_ws,
             float* __restrict__ zacc) {
  __shared__ float zpart[8];
  const int lane = threadIdx.x & 63;
  const int b    = threadIdx.x >> 6;    // batch

  int   cnt  = 0;
  float zsum = 0.f;
  const unsigned long long below = (1ULL << lane) - 1ULL;

  for (int n0 = 0; n0 < N_; n0 += 64) {
    const int   t    = b*N_ + n0 + lane;
    const int   idx  = idx_ws[t];
    const float z    = z_ws[t];
    zsum += z * z;

    unsigned long long bb[6];
    #pragma unroll
    for (int k = 0; k < 6; ++k) bb[k] = __ballot((idx >> k) & 1);

    unsigned long long m_tok = ~0ULL, m_exp = ~0ULL;
    #pragma unroll
    for (int k = 0; k < 6; ++k) {
      m_tok &= ((idx  >> k) & 1) ? bb[k] : ~bb[k];
      m_exp &= ((lane >> k) & 1) ? bb[k] : ~bb[k];
    }

    const int rank = __popcll(m_tok & below);
    const int base = __shfl(cnt, idx);
    const int pos  = base + rank;
    cnt += __popcll(m_exp);

    code_ws[t] = (u32)idx | ((u32)((pos < CAP_) ? pos : 255) << 8);
  }

  #pragma unroll
  for (int m = 1; m < 64; m <<= 1) zsum += __shfl_xor(zsum, m);
  if (lane == 0) zpart[b] = zsum;
  __syncthreads();
  if (threadIdx.x == 0) {
    float s = 0.f;
    #pragma unroll
    for (int i = 0; i < 8; ++i) s += zpart[i];
    zacc[0] = s * (1.0f / (float)NTOK);
  }
}

// K3: value-fill. Each thread owns one 16B granule of dispatch AND the matching
// granule of combine; value derived from code[t] (wave-uniform, L2-hot).
// Pure-write stream at fill-kernel rate.
__global__ __launch_bounds__(256)
void k_fillv(const u32* __restrict__ code_ws, const float* __restrict__ gate_ws,
             const float* __restrict__ zacc, float* __restrict__ out) {
  const size_t g0     = (size_t)blockIdx.x * 256 + threadIdx.x;
  const size_t ngran  = MASK_ELEMS / 4;              // 16777216 granules per array
  const size_t stride = (size_t)FILLV_BLOCKS * 256;
  f32x4* disp = (f32x4*)out;
  f32x4* comb = (f32x4*)(out + MASK_ELEMS);

  for (size_t g = g0; g < ngran; g += stride) {
    const int t  = (int)(g >> 10);                   // 1024 granules per token
    const u32 r  = (u32)g & 1023u;
    const int e  = (int)(r >> 4);
    const int c0 = (int)(r & 15u) << 2;
    const u32 code = code_ws[t];
    f32x4 dv = {0.f, 0.f, 0.f, 0.f};
    f32x4 cv = {0.f, 0.f, 0.f, 0.f};
    if (e == (int)(code & 0xFFu)) {
      const int p = (int)(code >> 8) - c0;
      if (0 <= p && p < 4) {
        dv[p] = 1.0f;
        cv[p] = gate_ws[t];
      }
    }
    __builtin_nontemporal_store(dv, disp + g);
    __builtin_nontemporal_store(cv, comb + g);
  }
  if (g0 == 0) out[2*MASK_ELEMS] = zacc[0];          // z-loss scalar
}

extern "C" void kernel_launch(void* const* d_in, const int* in_sizes, int n_in,
                              void* d_out, int out_size, void* d_ws, size_t ws_size,
                              hipStream_t stream) {
  const float* X = (const float*)d_in[0];   // [8,2048,2048]
  const float* W = (const float*)d_in[1];   // [2048,64]
  float* out = (float*)d_out;               // dispatch | combine | z_loss

  char* wsb = (char*)d_ws;
  u32*   whi     = (u32*)  (wsb);            // 256 KB
  u32*   wlo     = (u32*)  (wsb + 262144);   // 256 KB
  float* gate_ws = (float*)(wsb + 524288);   // 64 KB
  int*   idx_ws  = (int*)  (wsb + 589824);   // 64 KB
  float* z_ws    = (float*)(wsb + 655360);   // 64 KB
  u32*   code_ws = (u32*)  (wsb + 720896);   // 64 KB
  float* zacc    = (float*)(wsb + 786432);   // 4 B

  hipLaunchKernelGGL(k_wconv, dim3(64), dim3(256), 0, stream, W, whi, wlo);
  hipLaunchKernelGGL(k_gemm, dim3(GEMM_BLOCKS), dim3(256), 0, stream,
                     X, whi, wlo, gate_ws, idx_ws, z_ws);
  hipLaunchKernelGGL(k_route, dim3(1), dim3(512), 0, stream,
                     gate_ws, idx_ws, z_ws, code_ws, zacc);
  hipLaunchKernelGGL(k_fillv, dim3(FILLV_BLOCKS), dim3(256), 0, stream,
                     code_ws, gate_ws, zacc, out);
}

// Round 7
// 141.606 us; speedup vs baseline: 1.2619x; 1.2619x over previous
//
#include <hip/hip_runtime.h>
#include <cstdint>
#include <cstddef>

#define B_ 8
#define N_ 2048
#define D_ 2048
#define E_ 64
#define CAP_ 64
#define NTOK (B_*N_)                  // 16384 tokens
#define GEMM_BLOCKS 256               // 64 tokens/block, 4 waves
#define FILL_BLOCKS 4096              // 128 KB contiguous per block, exact division
#define DC 64                         // d-tile
#define NTILE (D_/DC)                 // 32
#define MASK_ELEMS ((size_t)NTOK*(size_t)E_*(size_t)CAP_)   // 67108864 per output

typedef float f32x4 __attribute__((ext_vector_type(4)));
typedef short bf16x8 __attribute__((ext_vector_type(8)));
typedef unsigned int u32;
typedef u32 u32x2 __attribute__((ext_vector_type(2)));

__device__ __forceinline__ u32 f2bf(float f) {          // RNE f32 -> bf16 bits
  u32 u = __float_as_uint(f);
  return (u + 0x7fffu + ((u >> 16) & 1u)) >> 16;
}
__device__ __forceinline__ float bf2f(u32 b) { return __uint_as_float(b << 16); }

// K0: W[2048][64] f32 -> WhiT/WloT bf16, transposed to [e][d] and tile-swizzled:
// 16B-granule index = (t*64 + e)*8 + (g ^ (e&7)), holding d = t*64+g*8..+7 of expert e.
__global__ __launch_bounds__(256)
void k_wconv(const float* __restrict__ W, u32* __restrict__ whi, u32* __restrict__ wlo) {
  const int i = blockIdx.x * 256 + threadIdx.x;   // 16384 = (t,e,g)
  const int g = i & 7, e = (i >> 3) & 63, t = i >> 9;
  const int d0 = t * DC + g * 8;
  const int dst = ((t * 64 + e) * 8 + (g ^ (e & 7))) * 4;  // in u32 (8 bf16 = 4 u32)
  #pragma unroll
  for (int jj = 0; jj < 4; ++jj) {
    const float x0 = W[(size_t)(d0 + 2*jj    ) * E_ + e];
    const float x1 = W[(size_t)(d0 + 2*jj + 1) * E_ + e];
    const u32 h0 = f2bf(x0), h1 = f2bf(x1);
    const u32 l0 = f2bf(x0 - bf2f(h0)), l1 = f2bf(x1 - bf2f(h1));
    whi[dst + jj] = h0 | (h1 << 16);
    wlo[dst + jj] = l0 | (l1 << 16);
  }
}

// K1: fused zero-fill + split-bf16 MFMA logits GEMM + per-token softmax stats.
// Fill branch: rocclr-style — each block owns a contiguous 128 KB span; per wave
// 4 x dwordx4 stores at immediate offsets (1 KB wave-contiguous each), 1 pointer
// add per 4 stores, exact trip count (no bounds checks) -> ~0.5 VALU/store.
__global__ __launch_bounds__(256)
void k_gemm_zero(const float* __restrict__ X, const u32* __restrict__ whi,
                 const u32* __restrict__ wlo, float* __restrict__ out,
                 float* __restrict__ gate_ws, int* __restrict__ idx_ws,
                 float* __restrict__ z_ws) {
  const int bid = blockIdx.x;
  if (bid >= GEMM_BLOCKS) {
    // ---- zero-fill: dispatch_mask + combine_array (+ z slot) ----
    const int zb   = bid - GEMM_BLOCKS;               // 0..4095
    const int tid  = threadIdx.x;
    const int wid  = tid >> 6, lane = tid & 63;
    const f32x4 z4 = {0.f, 0.f, 0.f, 0.f};
    f32x4* p = (f32x4*)out + ((size_t)zb*8192 + wid*256 + lane);
    #pragma unroll
    for (int j = 0; j < 8; ++j) {                     // 8 x 16KB chunks per block
      __builtin_nontemporal_store(z4, p +   0);       // imm offset 0
      __builtin_nontemporal_store(z4, p +  64);       // imm offset 1024
      __builtin_nontemporal_store(z4, p + 128);       // imm offset 2048
      __builtin_nontemporal_store(z4, p + 192);       // imm offset 3072
      p += 1024;
    }
    if (zb == 0 && tid == 0) out[2*MASK_ELEMS] = 0.f; // z-loss slot
    return;
  }

  // buf layout per 32KB half: XH 0 | XL 8192 | WH 16384 | WL 24576
  __shared__ __align__(16) char lds[2][32768];
  const int tid  = threadIdx.x;
  const int lane = tid & 63;
  const int wid  = __builtin_amdgcn_readfirstlane(tid >> 6);
  const int tokbase = bid * 64;
  const int woff = wid * 16;            // wave's 16-token panel
  const int rA = lane & 15, kg = lane >> 4;

  // X staging map: p in 0..3 -> chunk c = p*256+tid ; row r=c>>4, f32x4-col q=c&15
  int xr_r[4], xr_q[4], xw_off[4];
  #pragma unroll
  for (int p = 0; p < 4; ++p) {
    const int c = p*256 + tid;
    const int r = c >> 4, q = c & 15;
    xr_r[p] = r; xr_q[p] = q;
    xw_off[p] = r*128 + (((q >> 1) ^ (r & 7)) << 4) + ((q & 1) << 3);
  }
  const f32x4* xg   = (const f32x4*)X;
  const f32x4* whi4 = (const f32x4*)whi;
  const f32x4* wlo4 = (const f32x4*)wlo;

  f32x4 xr[4], wr[4];

#define XW_LOAD(t)                                                            \
  { _Pragma("unroll")                                                         \
    for (int p = 0; p < 4; ++p)                                               \
      xr[p] = xg[(size_t)(tokbase + xr_r[p])*512 + (size_t)(t)*16 + xr_q[p]]; \
    wr[0] = whi4[(size_t)(t)*512 + tid];                                      \
    wr[1] = whi4[(size_t)(t)*512 + 256 + tid];                                \
    wr[2] = wlo4[(size_t)(t)*512 + tid];                                      \
    wr[3] = wlo4[(size_t)(t)*512 + 256 + tid]; }

#define XW_STORE(buf)                                                         \
  { char* bq = lds[buf];                                                      \
    _Pragma("unroll")                                                         \
    for (int p = 0; p < 4; ++p) {                                             \
      const u32 h0 = f2bf(xr[p][0]), h1 = f2bf(xr[p][1]);                     \
      const u32 h2 = f2bf(xr[p][2]), h3 = f2bf(xr[p][3]);                     \
      const u32 l0 = f2bf(xr[p][0] - bf2f(h0)), l1 = f2bf(xr[p][1] - bf2f(h1)); \
      const u32 l2 = f2bf(xr[p][2] - bf2f(h2)), l3 = f2bf(xr[p][3] - bf2f(h3)); \
      u32x2 hp; hp[0] = h0 | (h1 << 16); hp[1] = h2 | (h3 << 16);             \
      u32x2 lp; lp[0] = l0 | (l1 << 16); lp[1] = l2 | (l3 << 16);             \
      *(u32x2*)(bq + xw_off[p])        = hp;                                  \
      *(u32x2*)(bq + 8192 + xw_off[p]) = lp;                                  \
    }                                                                         \
    *(f32x4*)(bq + 16384 +        tid*16) = wr[0];                            \
    *(f32x4*)(bq + 16384 + 4096 + tid*16) = wr[1];                            \
    *(f32x4*)(bq + 24576 +        tid*16) = wr[2];                            \
    *(f32x4*)(bq + 24576 + 4096 + tid*16) = wr[3]; }

  XW_LOAD(0);
  XW_STORE(0);
  __syncthreads();

  f32x4 acc[4];
  #pragma unroll
  for (int eb = 0; eb < 4; ++eb) { acc[eb][0]=0.f; acc[eb][1]=0.f; acc[eb][2]=0.f; acc[eb][3]=0.f; }

  const int tokrow = woff + rA;
  for (int t = 0; t < NTILE; ++t) {
    if (t + 1 < NTILE) XW_LOAD(t + 1);

    const char* bp = lds[t & 1];
    #pragma unroll
    for (int kk = 0; kk < 2; ++kk) {
      const int gA = ((kk*4 + kg) ^ (rA & 7)) << 4;       // tokrow&7 == rA&7
      const bf16x8 Ah = *(const bf16x8*)(bp +        tokrow*128 + gA);
      const bf16x8 Al = *(const bf16x8*)(bp + 8192 + tokrow*128 + gA);
      #pragma unroll
      for (int eb = 0; eb < 4; ++eb) {
        const int e  = eb*16 + rA;
        const int gB = ((kk*4 + kg) ^ (e & 7)) << 4;
        const bf16x8 Bh = *(const bf16x8*)(bp + 16384 + e*128 + gB);
        const bf16x8 Bl = *(const bf16x8*)(bp + 24576 + e*128 + gB);
        acc[eb] = __builtin_amdgcn_mfma_f32_16x16x32_bf16(Ah, Bh, acc[eb], 0, 0, 0);
        acc[eb] = __builtin_amdgcn_mfma_f32_16x16x32_bf16(Ah, Bl, acc[eb], 0, 0, 0);
        acc[eb] = __builtin_amdgcn_mfma_f32_16x16x32_bf16(Al, Bh, acc[eb], 0, 0, 0);
        acc[eb] = __builtin_amdgcn_mfma_f32_16x16x32_bf16(Al, Bl, acc[eb], 0, 0, 0);
      }
    }

    if (t + 1 < NTILE) XW_STORE((t + 1) & 1);
    __syncthreads();
  }

  // ---- epilogue: logits -> LDS [64 tok][65], per-wave butterfly softmax ----
  float* Lg = (float*)&lds[0][0];
  // C/D layout: col = lane&15 (expert within block), row = (lane>>4)*4 + reg
  #pragma unroll
  for (int eb = 0; eb < 4; ++eb)
    #pragma unroll
    for (int r = 0; r < 4; ++r)
      Lg[(woff + kg*4 + r)*65 + eb*16 + rA] = acc[eb][r];
  __syncthreads();

  #pragma unroll 1
  for (int i = 0; i < 16; ++i) {
    const int tkn = woff + i;
    const float v = Lg[tkn*65 + lane];       // lane = expert
    float vmax = v; int vidx = lane;
    #pragma unroll
    for (int m = 1; m < 64; m <<= 1) {
      const float om = __shfl_xor(vmax, m);
      const int   oi = __shfl_xor(vidx, m);
      if (om > vmax || (om == vmax && oi < vidx)) { vmax = om; vidx = oi; }
    }
    float se = expf(v - vmax);
    #pragma unroll
    for (int m = 1; m < 64; m <<= 1) se += __shfl_xor(se, m);
    if (lane == 0) {
      const int row = tokbase + tkn;
      gate_ws[row] = 1.0f / se;              // max softmax prob
      idx_ws[row]  = vidx;                   // argmax, first occurrence
      z_ws[row]    = vmax + logf(se);        // logsumexp
    }
  }
#undef XW_LOAD
#undef XW_STORE
}

// K2: per-batch position-in-expert cumsum via bit-sliced ballots + scatter + z-loss.
__global__ __launch_bounds__(64)
void k_route(const float* __restrict__ gate_ws, const int* __restrict__ idx_ws,
             const float* __restrict__ z_ws, float* __restrict__ out) {
  const int b    = blockIdx.x;
  const int lane = threadIdx.x;
  float* dispatch = out;
  float* combine  = out + MASK_ELEMS;

  int   cnt  = 0;
  float zsum = 0.f;
  const unsigned long long below = (1ULL << lane) - 1ULL;

  for (int n0 = 0; n0 < N_; n0 += 64) {
    const int   t    = b*N_ + n0 + lane;
    const int   idx  = idx_ws[t];
    const float gate = gate_ws[t];
    const float z    = z_ws[t];
    zsum += z * z;

    unsigned long long bb[6];
    #pragma unroll
    for (int k = 0; k < 6; ++k) bb[k] = __ballot((idx >> k) & 1);

    unsigned long long m_tok = ~0ULL, m_exp = ~0ULL;
    #pragma unroll
    for (int k = 0; k < 6; ++k) {
      m_tok &= ((idx  >> k) & 1) ? bb[k] : ~bb[k];
      m_exp &= ((lane >> k) & 1) ? bb[k] : ~bb[k];
    }

    const int rank = __popcll(m_tok & below);
    const int base = __shfl(cnt, idx);
    const int pos  = base + rank;
    cnt += __popcll(m_exp);

    if (pos < CAP_) {
      const size_t o = (((size_t)t)*E_ + (size_t)idx)*CAP_ + (size_t)pos;
      dispatch[o] = 1.0f;
      combine[o]  = gate;
    }
  }

  #pragma unroll
  for (int m = 1; m < 64; m <<= 1) zsum += __shfl_xor(zsum, m);
  if (lane == 0) atomicAdd(out + 2*MASK_ELEMS, zsum * (1.0f / (float)NTOK));
}

extern "C" void kernel_launch(void* const* d_in, const int* in_sizes, int n_in,
                              void* d_out, int out_size, void* d_ws, size_t ws_size,
                              hipStream_t stream) {
  const float* X = (const float*)d_in[0];   // [8,2048,2048]
  const float* W = (const float*)d_in[1];   // [2048,64]
  float* out = (float*)d_out;               // dispatch | combine | z_loss

  char* wsb = (char*)d_ws;
  u32*   whi     = (u32*)  (wsb);            // 256 KB
  u32*   wlo     = (u32*)  (wsb + 262144);   // 256 KB
  float* gate_ws = (float*)(wsb + 524288);   // 64 KB
  int*   idx_ws  = (int*)  (wsb + 589824);   // 64 KB
  float* z_ws    = (float*)(wsb + 655360);   // 64 KB

  hipLaunchKernelGGL(k_wconv, dim3(64), dim3(256), 0, stream, W, whi, wlo);
  hipLaunchKernelGGL(k_gemm_zero, dim3(GEMM_BLOCKS + FILL_BLOCKS), dim3(256), 0, stream,
                     X, whi, wlo, out, gate_ws, idx_ws, z_ws);
  hipLaunchKernelGGL(k_route, dim3(B_), dim3(64), 0, stream,
                     gate_ws, idx_ws, z_ws, out);
}